// Round 4
// baseline (781.482 us; speedup 1.0000x reference)
//
#include <hip/hip_runtime.h>
#include <math.h>
#include <stdint.h>

#define NIMG   8
#define NA     30000      // H*W*A = 100*100*3
#define PRE_N  2000
#define POST_N 1000
#define NMS_TH 0.7f
#define DCLIP  4.135166556742356f   // log(1000/16)
#define IMGF   1600.0f
#define IMGM1  1599.0f

// ws layout (floats): boxes [8][2000][4] @0, scores [8][2000] @64000,
//                     valid(int) [8][2000] @80000,
//                     mask(u64)  [8][2000][32] @96000 floats (byte 384000)

// ---------------------------------------------------------------------------
// Kernel 1: per-image top-2000 (by logit desc, idx asc), decode, clip, valid.
// (unchanged — verified bit-exact)
// ---------------------------------------------------------------------------
__global__ __launch_bounds__(1024) void topk_decode(
    const float* __restrict__ obj,    // [8][3][100][100]
    const float* __restrict__ breg,   // [8][12][100][100]
    float* __restrict__ wsBoxes, float* __restrict__ wsScores,
    int* __restrict__ wsValid)
{
    const int n   = blockIdx.x;
    const int tid = threadIdx.x;

    __shared__ uint64_t sel[2048];
    __shared__ uint64_t bnd[4096];
    __shared__ unsigned int scal[4];

    unsigned int* hist = (unsigned int*)bnd;
    unsigned int* part = ((unsigned int*)bnd) + 4096;

    for (int b = tid; b < 4096; b += 1024) hist[b] = 0u;
    if (tid < 4) scal[tid] = 0u;
    __syncthreads();

    const float* objn = obj + n * NA;

    for (int j = tid; j < NA; j += 1024) {
        unsigned int u = __float_as_uint(objn[j]);
        unsigned int k = (u & 0x80000000u) ? ~u : (u | 0x80000000u);
        atomicAdd(&hist[k >> 20], 1u);
    }
    __syncthreads();

    unsigned int c0 = hist[tid*4+0], c1 = hist[tid*4+1],
                 c2 = hist[tid*4+2], c3 = hist[tid*4+3];
    part[tid] = c0 + c1 + c2 + c3;
    __syncthreads();
    for (int off = 1; off < 1024; off <<= 1) {
        unsigned int v = (tid + off < 1024) ? part[tid + off] : 0u;
        __syncthreads();
        part[tid] += v;
        __syncthreads();
    }
    unsigned int after = (tid < 1023) ? part[tid + 1] : 0u;
    {
        unsigned int S3 = after + c3;
        unsigned int S2 = S3 + c2;
        unsigned int S1 = S2 + c1;
        unsigned int S0 = S1 + c0;
        if (S3 >= PRE_N && after < PRE_N) { scal[2] = tid*4+3; scal[3] = after; }
        if (S2 >= PRE_N && S3    < PRE_N) { scal[2] = tid*4+2; scal[3] = S3; }
        if (S1 >= PRE_N && S2    < PRE_N) { scal[2] = tid*4+1; scal[3] = S2; }
        if (S0 >= PRE_N && S1    < PRE_N) { scal[2] = tid*4+0; scal[3] = S1; }
    }
    __syncthreads();
    const unsigned int bstar   = scal[2];
    const unsigned int c_above = scal[3];

    for (int j = tid; j < NA; j += 1024) {
        unsigned int u = __float_as_uint(objn[j]);
        unsigned int k = (u & 0x80000000u) ? ~u : (u | 0x80000000u);
        unsigned int bin = k >> 20;
        if (bin < bstar) continue;
        int a = j / 10000, t = j - a * 10000;
        unsigned int i = (unsigned int)(t * 3 + a);
        uint64_t key = (((uint64_t)(~k)) << 32) | (uint64_t)i;
        if (bin > bstar) {
            unsigned int p = atomicAdd(&scal[0], 1u);
            sel[p] = key;
        } else {
            unsigned int p = atomicAdd(&scal[1], 1u);
            if (p < 4096u) bnd[p] = key;
        }
    }
    __syncthreads();

    unsigned int nbnd = scal[1]; if (nbnd > 4096u) nbnd = 4096u;
    const unsigned int m = PRE_N - c_above;

    unsigned int P2 = 1; while (P2 < nbnd) P2 <<= 1;
    if (P2 < 2u) P2 = 2u;
    for (unsigned int i = nbnd + tid; i < P2; i += 1024) bnd[i] = ~0ull;
    __syncthreads();
    for (unsigned int ks = 2; ks <= P2; ks <<= 1) {
        for (unsigned int js = ks >> 1; js > 0; js >>= 1) {
            for (unsigned int i = tid; i < P2; i += 1024) {
                unsigned int ix = i ^ js;
                if (ix > i) {
                    uint64_t a0 = bnd[i], a1 = bnd[ix];
                    bool up = ((i & ks) == 0u);
                    bool sw = up ? (a0 > a1) : (a0 < a1);
                    if (sw) { bnd[i] = a1; bnd[ix] = a0; }
                }
            }
            __syncthreads();
        }
    }
    for (unsigned int r = tid; r < m; r += 1024) sel[c_above + r] = bnd[r];
    for (unsigned int r = PRE_N + tid; r < 2048; r += 1024) sel[r] = ~0ull;
    __syncthreads();
    for (unsigned int ks = 2; ks <= 2048; ks <<= 1) {
        for (unsigned int js = ks >> 1; js > 0; js >>= 1) {
            for (unsigned int i = tid; i < 2048; i += 1024) {
                unsigned int ix = i ^ js;
                if (ix > i) {
                    uint64_t a0 = sel[i], a1 = sel[ix];
                    bool up = ((i & ks) == 0u);
                    bool sw = up ? (a0 > a1) : (a0 < a1);
                    if (sw) { sel[i] = a1; sel[ix] = a0; }
                }
            }
            __syncthreads();
        }
    }

    for (int r = tid; r < PRE_N; r += 1024) {
        uint64_t key = sel[r];
        unsigned int idx = (unsigned int)key;
        unsigned int k   = ~((unsigned int)(key >> 32));
        unsigned int u   = (k & 0x80000000u) ? (k & 0x7fffffffu) : ~k;
        float logit = __uint_as_float(u);
        float score = 1.0f / (1.0f + expf(-logit));

        int a = idx % 3, t = idx / 3, w = t % 100, h = t / 100;
        const float* bp = breg + n*120000 + (a*4)*10000 + t;
        float dx = bp[0], dy = bp[10000], dw = bp[20000], dh = bp[30000];

        float half = (a == 0) ? 32.0f : ((a == 1) ? 64.0f : 128.0f);
        float cx = w * 16.0f + 8.0f, cy = h * 16.0f + 8.0f;
        float x1 = cx - half, y1 = cy - half, x2 = cx + half, y2 = cy + half;
        float wd = x2 - x1 + 1.0f, hg = y2 - y1 + 1.0f;
        float cxr = x1 + 0.5f * wd, cyr = y1 + 0.5f * hg;
        dw = fminf(dw, DCLIP); dh = fminf(dh, DCLIP);
        float pcx = dx * wd + cxr, pcy = dy * hg + cyr;
        float pw = expf(dw) * wd, ph = expf(dh) * hg;
        float px1 = pcx - 0.5f * pw, py1 = pcy - 0.5f * ph;
        float px2 = pcx + 0.5f * pw - 1.0f, py2 = pcy + 0.5f * ph - 1.0f;
        px1 = fminf(fmaxf(px1, 0.0f), IMGM1);
        px2 = fminf(fmaxf(px2, 0.0f), IMGM1);
        py1 = fminf(fmaxf(py1, 0.0f), IMGM1);
        py2 = fminf(fmaxf(py2, 0.0f), IMGM1);
        float wss = px2 - px1 + 1.0f, hss = py2 - py1 + 1.0f;
        float xc = px1 + wss * 0.5f, yc = py1 + hss * 0.5f;
        int valid = (wss >= 0.0f) && (hss >= 0.0f) && (xc < IMGF) && (yc < IMGF);

        float4 bx = make_float4(px1, py1, px2, py2);
        ((float4*)wsBoxes)[n * PRE_N + r] = bx;
        wsScores[n * PRE_N + r] = score;
        wsValid [n * PRE_N + r] = valid;
    }
}

// ---------------------------------------------------------------------------
// Kernel 2: parallel IoU suppression bit-matrix. block = (image, row-tile of 64).
// mask[n][r][w] bit c set iff j = w*64+c > r, j < 2000, iou(r,j) > thresh.
// ---------------------------------------------------------------------------
__global__ __launch_bounds__(256) void nms_mask(
    const float* __restrict__ wsBoxes, uint64_t* __restrict__ mask)
{
    const int blk  = blockIdx.x;
    const int n    = blk >> 5;
    const int i_t  = blk & 31;
    const int tid  = threadIdx.x;
    const int lane = tid & 63;
    const int wv   = tid >> 6;   // 0..3

    __shared__ float cx1[PRE_N], cy1[PRE_N], cx2[PRE_N], cy2[PRE_N], car[PRE_N];
    __shared__ uint64_t tile[64 * 32];   // [row_local][word]

    for (int i = tid; i < PRE_N; i += 256) {
        float4 b = ((const float4*)wsBoxes)[n * PRE_N + i];
        cx1[i] = b.x; cy1[i] = b.y; cx2[i] = b.z; cy2[i] = b.w;
        car[i] = (b.z - b.x + 1.0f) * (b.w - b.y + 1.0f);
    }
    __syncthreads();

    const int r = i_t * 64 + lane;
    const bool rok = (r < PRE_N);
    float x1r = 0.f, y1r = 0.f, x2r = 0.f, y2r = 0.f, ar = 0.f;
    if (rok) { x1r = cx1[r]; y1r = cy1[r]; x2r = cx2[r]; y2r = cy2[r]; ar = car[r]; }

    for (int j_t = wv; j_t < 32; j_t += 4) {
        uint64_t wbits = 0ull;
        if (rok && j_t >= i_t) {
            const int jbase = j_t * 64;
            for (int c = 0; c < 64; ++c) {
                const int j = jbase + c;
                if (j > r && j < PRE_N) {
                    float xx1 = fmaxf(x1r, cx1[j]), yy1 = fmaxf(y1r, cy1[j]);
                    float xx2 = fminf(x2r, cx2[j]), yy2 = fminf(y2r, cy2[j]);
                    float ww = fmaxf(xx2 - xx1 + 1.0f, 0.0f);
                    float hh = fmaxf(yy2 - yy1 + 1.0f, 0.0f);
                    float inter = ww * hh;
                    float iou = inter / (ar + car[j] - inter);
                    if (iou > NMS_TH) wbits |= (1ull << c);
                }
            }
        }
        tile[lane * 32 + j_t] = wbits;
    }
    __syncthreads();

    uint64_t* dst = mask + ((size_t)n * PRE_N + (size_t)i_t * 64) * 32;
    const int lim = (i_t == 31) ? (16 * 32) : (64 * 32);  // rows >= 2000 don't exist
    for (int q = tid; q < lim; q += 256) dst[q] = tile[q];
}

// ---------------------------------------------------------------------------
// Kernel 3: serial greedy scan over the bit-matrix. Prefetch ring is 32
// INDIVIDUALLY-NAMED u64 registers (macro-generated) — arrays got demoted to
// scratch by the compiler (VGPR_Count=40 in R3 proved it); named scalars
// cannot be. 32 coalesced 256B loads stay in flight.
// ---------------------------------------------------------------------------
__global__ __launch_bounds__(256) void nms_scan_select(
    const float* __restrict__ wsBoxes, const float* __restrict__ wsScores,
    const int* __restrict__ wsValid, const uint64_t* __restrict__ mask,
    float* __restrict__ out)
{
    const int n   = blockIdx.x;
    const int tid = threadIdx.x;

    __shared__ unsigned char invb[256];
    __shared__ uint64_t keepw[32];
    __shared__ int sscan[256];

    // build "initially removed" (= !valid) bits, 8 boxes per thread
    unsigned int byte = 0u;
    if (tid < PRE_N / 8) {
        for (int q = 0; q < 8; ++q)
            byte |= (wsValid[n * PRE_N + tid * 8 + q] ? 0u : 1u) << q;
    }
    invb[tid] = (unsigned char)byte;
    __syncthreads();

    if (tid < 64) {
        const int wl = tid & 31;     // lanes 32..63 mirror 0..31
        uint64_t removed = ((const uint64_t*)invb)[wl];
        const uint64_t* rbase = mask + (size_t)n * PRE_N * 32 + wl;

        uint64_t q0,q1,q2,q3,q4,q5,q6,q7,q8,q9,q10,q11,q12,q13,q14,q15,
                 q16,q17,q18,q19,q20,q21,q22,q23,q24,q25,q26,q27,q28,q29,q30,q31;
        #define LOADQ(d) q##d = rbase[(size_t)(d) * 32];
        LOADQ(0) LOADQ(1) LOADQ(2) LOADQ(3) LOADQ(4) LOADQ(5) LOADQ(6) LOADQ(7)
        LOADQ(8) LOADQ(9) LOADQ(10) LOADQ(11) LOADQ(12) LOADQ(13) LOADQ(14) LOADQ(15)
        LOADQ(16) LOADQ(17) LOADQ(18) LOADQ(19) LOADQ(20) LOADQ(21) LOADQ(22) LOADQ(23)
        LOADQ(24) LOADQ(25) LOADQ(26) LOADQ(27) LOADQ(28) LOADQ(29) LOADQ(30) LOADQ(31)
        #undef LOADQ

        for (int ib = 0; ib < 2048; ib += 32) {
            #define STEP(d) { \
                const int i = ib + (d); \
                if (i < PRE_N) { \
                    uint64_t ri = q##d; \
                    const int w = i >> 6, b = i & 63; \
                    unsigned int lo = (unsigned int)removed; \
                    unsigned int hi = (unsigned int)(removed >> 32); \
                    unsigned int s  = (b & 32) ? hi : lo; \
                    unsigned int wordp = \
                        (unsigned int)__builtin_amdgcn_readlane((int)s, w); \
                    bool dead = (wordp >> (b & 31)) & 1u; \
                    removed |= dead ? 0ull : ri; \
                    if (i + 32 < PRE_N) q##d = rbase[(size_t)(i + 32) * 32]; \
                } \
            }
            STEP(0) STEP(1) STEP(2) STEP(3) STEP(4) STEP(5) STEP(6) STEP(7)
            STEP(8) STEP(9) STEP(10) STEP(11) STEP(12) STEP(13) STEP(14) STEP(15)
            STEP(16) STEP(17) STEP(18) STEP(19) STEP(20) STEP(21) STEP(22) STEP(23)
            STEP(24) STEP(25) STEP(26) STEP(27) STEP(28) STEP(29) STEP(30) STEP(31)
            #undef STEP
        }
        if (tid < 32) {
            uint64_t kw = ~removed;
            if (wl == 31) kw &= 0xFFFFull;   // rows 2000..2047 don't exist
            keepw[wl] = kw;
        }
    }
    __syncthreads();

    // prefix scan of keep flags, 8 per thread
    int c[8]; const int base8 = tid * 8;
    int lsum = 0;
    for (int q = 0; q < 8; ++q) {
        const int i = base8 + q;
        c[q] = (i < PRE_N) ? (int)((keepw[i >> 6] >> (i & 63)) & 1ull) : 0;
        lsum += c[q];
    }
    sscan[tid] = lsum;
    __syncthreads();
    for (int off = 1; off < 256; off <<= 1) {
        int v = (tid >= off) ? sscan[tid - off] : 0;
        __syncthreads();
        sscan[tid] += v;
        __syncthreads();
    }
    const int excl  = sscan[tid] - lsum;
    const int total = sscan[255];

    float* ob  = out + n * POST_N * 4;
    float* osc = out + NIMG * POST_N * 4 + n * POST_N;
    float* ovd = out + NIMG * POST_N * 5 + n * POST_N;

    for (int i = tid; i < POST_N * 4; i += 256) ob[i] = 0.0f;
    for (int i = tid; i < POST_N; i += 256) osc[i] = 0.0f;
    const int lim = min(total, POST_N);
    for (int i = tid; i < POST_N; i += 256) ovd[i] = (i < lim) ? 1.0f : 0.0f;
    __syncthreads();

    int run = excl;
    for (int q = 0; q < 8; ++q) {
        const int i = base8 + q;
        if (i < PRE_N && c[q]) {
            if (run < POST_N) {
                float4 b = ((const float4*)wsBoxes)[n * PRE_N + i];
                ob[run * 4 + 0] = b.x;
                ob[run * 4 + 1] = b.y;
                ob[run * 4 + 2] = b.z;
                ob[run * 4 + 3] = b.w;
                osc[run] = wsScores[n * PRE_N + i];
            }
            run++;
        }
    }
}

extern "C" void kernel_launch(void* const* d_in, const int* in_sizes, int n_in,
                              void* d_out, int out_size, void* d_ws, size_t ws_size,
                              hipStream_t stream) {
    const float* obj  = (const float*)d_in[0];
    const float* breg = (const float*)d_in[1];
    // d_in[2] anchors unused (computed inline, exact in f32)
    float* ws        = (float*)d_ws;
    float* wsBoxes   = ws;                      // 64000 floats
    float* wsScores  = ws + 64000;              // 16000 floats
    int*   wsValid   = (int*)(ws + 80000);      // 16000 ints
    uint64_t* wsMask = (uint64_t*)(ws + 96000); // 8*2000*32 u64 = 4 MB

    topk_decode<<<NIMG, 1024, 0, stream>>>(obj, breg, wsBoxes, wsScores, wsValid);
    nms_mask<<<NIMG * 32, 256, 0, stream>>>(wsBoxes, wsMask);
    nms_scan_select<<<NIMG, 256, 0, stream>>>(wsBoxes, wsScores, wsValid, wsMask,
                                              (float*)d_out);
}

// Round 5
// 295.837 us; speedup vs baseline: 2.6416x; 2.6416x over previous
//
#include <hip/hip_runtime.h>
#include <math.h>
#include <stdint.h>

#define NIMG   8
#define NA     30000      // H*W*A = 100*100*3
#define PRE_N  2000
#define POST_N 1000
#define NMS_TH 0.7f
#define DCLIP  4.135166556742356f   // log(1000/16)
#define IMGF   1600.0f
#define IMGM1  1599.0f

// ws layout (floats): boxes [8][2000][4] @0, scores [8][2000] @64000,
//                     valid(int) [8][2000] @80000,
//                     mask(u64)  [8][2000][32] @96000 floats (byte 384000)

// ---------------------------------------------------------------------------
// Kernel 1: per-image top-2000 (by logit desc, idx asc), decode, clip, valid.
// (unchanged — verified bit-exact)
// ---------------------------------------------------------------------------
__global__ __launch_bounds__(1024) void topk_decode(
    const float* __restrict__ obj,    // [8][3][100][100]
    const float* __restrict__ breg,   // [8][12][100][100]
    float* __restrict__ wsBoxes, float* __restrict__ wsScores,
    int* __restrict__ wsValid)
{
    const int n   = blockIdx.x;
    const int tid = threadIdx.x;

    __shared__ uint64_t sel[2048];
    __shared__ uint64_t bnd[4096];
    __shared__ unsigned int scal[4];

    unsigned int* hist = (unsigned int*)bnd;
    unsigned int* part = ((unsigned int*)bnd) + 4096;

    for (int b = tid; b < 4096; b += 1024) hist[b] = 0u;
    if (tid < 4) scal[tid] = 0u;
    __syncthreads();

    const float* objn = obj + n * NA;

    for (int j = tid; j < NA; j += 1024) {
        unsigned int u = __float_as_uint(objn[j]);
        unsigned int k = (u & 0x80000000u) ? ~u : (u | 0x80000000u);
        atomicAdd(&hist[k >> 20], 1u);
    }
    __syncthreads();

    unsigned int c0 = hist[tid*4+0], c1 = hist[tid*4+1],
                 c2 = hist[tid*4+2], c3 = hist[tid*4+3];
    part[tid] = c0 + c1 + c2 + c3;
    __syncthreads();
    for (int off = 1; off < 1024; off <<= 1) {
        unsigned int v = (tid + off < 1024) ? part[tid + off] : 0u;
        __syncthreads();
        part[tid] += v;
        __syncthreads();
    }
    unsigned int after = (tid < 1023) ? part[tid + 1] : 0u;
    {
        unsigned int S3 = after + c3;
        unsigned int S2 = S3 + c2;
        unsigned int S1 = S2 + c1;
        unsigned int S0 = S1 + c0;
        if (S3 >= PRE_N && after < PRE_N) { scal[2] = tid*4+3; scal[3] = after; }
        if (S2 >= PRE_N && S3    < PRE_N) { scal[2] = tid*4+2; scal[3] = S3; }
        if (S1 >= PRE_N && S2    < PRE_N) { scal[2] = tid*4+1; scal[3] = S2; }
        if (S0 >= PRE_N && S1    < PRE_N) { scal[2] = tid*4+0; scal[3] = S1; }
    }
    __syncthreads();
    const unsigned int bstar   = scal[2];
    const unsigned int c_above = scal[3];

    for (int j = tid; j < NA; j += 1024) {
        unsigned int u = __float_as_uint(objn[j]);
        unsigned int k = (u & 0x80000000u) ? ~u : (u | 0x80000000u);
        unsigned int bin = k >> 20;
        if (bin < bstar) continue;
        int a = j / 10000, t = j - a * 10000;
        unsigned int i = (unsigned int)(t * 3 + a);
        uint64_t key = (((uint64_t)(~k)) << 32) | (uint64_t)i;
        if (bin > bstar) {
            unsigned int p = atomicAdd(&scal[0], 1u);
            sel[p] = key;
        } else {
            unsigned int p = atomicAdd(&scal[1], 1u);
            if (p < 4096u) bnd[p] = key;
        }
    }
    __syncthreads();

    unsigned int nbnd = scal[1]; if (nbnd > 4096u) nbnd = 4096u;
    const unsigned int m = PRE_N - c_above;

    unsigned int P2 = 1; while (P2 < nbnd) P2 <<= 1;
    if (P2 < 2u) P2 = 2u;
    for (unsigned int i = nbnd + tid; i < P2; i += 1024) bnd[i] = ~0ull;
    __syncthreads();
    for (unsigned int ks = 2; ks <= P2; ks <<= 1) {
        for (unsigned int js = ks >> 1; js > 0; js >>= 1) {
            for (unsigned int i = tid; i < P2; i += 1024) {
                unsigned int ix = i ^ js;
                if (ix > i) {
                    uint64_t a0 = bnd[i], a1 = bnd[ix];
                    bool up = ((i & ks) == 0u);
                    bool sw = up ? (a0 > a1) : (a0 < a1);
                    if (sw) { bnd[i] = a1; bnd[ix] = a0; }
                }
            }
            __syncthreads();
        }
    }
    for (unsigned int r = tid; r < m; r += 1024) sel[c_above + r] = bnd[r];
    for (unsigned int r = PRE_N + tid; r < 2048; r += 1024) sel[r] = ~0ull;
    __syncthreads();
    for (unsigned int ks = 2; ks <= 2048; ks <<= 1) {
        for (unsigned int js = ks >> 1; js > 0; js >>= 1) {
            for (unsigned int i = tid; i < 2048; i += 1024) {
                unsigned int ix = i ^ js;
                if (ix > i) {
                    uint64_t a0 = sel[i], a1 = sel[ix];
                    bool up = ((i & ks) == 0u);
                    bool sw = up ? (a0 > a1) : (a0 < a1);
                    if (sw) { sel[i] = a1; sel[ix] = a0; }
                }
            }
            __syncthreads();
        }
    }

    for (int r = tid; r < PRE_N; r += 1024) {
        uint64_t key = sel[r];
        unsigned int idx = (unsigned int)key;
        unsigned int k   = ~((unsigned int)(key >> 32));
        unsigned int u   = (k & 0x80000000u) ? (k & 0x7fffffffu) : ~k;
        float logit = __uint_as_float(u);
        float score = 1.0f / (1.0f + expf(-logit));

        int a = idx % 3, t = idx / 3, w = t % 100, h = t / 100;
        const float* bp = breg + n*120000 + (a*4)*10000 + t;
        float dx = bp[0], dy = bp[10000], dw = bp[20000], dh = bp[30000];

        float half = (a == 0) ? 32.0f : ((a == 1) ? 64.0f : 128.0f);
        float cx = w * 16.0f + 8.0f, cy = h * 16.0f + 8.0f;
        float x1 = cx - half, y1 = cy - half, x2 = cx + half, y2 = cy + half;
        float wd = x2 - x1 + 1.0f, hg = y2 - y1 + 1.0f;
        float cxr = x1 + 0.5f * wd, cyr = y1 + 0.5f * hg;
        dw = fminf(dw, DCLIP); dh = fminf(dh, DCLIP);
        float pcx = dx * wd + cxr, pcy = dy * hg + cyr;
        float pw = expf(dw) * wd, ph = expf(dh) * hg;
        float px1 = pcx - 0.5f * pw, py1 = pcy - 0.5f * ph;
        float px2 = pcx + 0.5f * pw - 1.0f, py2 = pcy + 0.5f * ph - 1.0f;
        px1 = fminf(fmaxf(px1, 0.0f), IMGM1);
        px2 = fminf(fmaxf(px2, 0.0f), IMGM1);
        py1 = fminf(fmaxf(py1, 0.0f), IMGM1);
        py2 = fminf(fmaxf(py2, 0.0f), IMGM1);
        float wss = px2 - px1 + 1.0f, hss = py2 - py1 + 1.0f;
        float xc = px1 + wss * 0.5f, yc = py1 + hss * 0.5f;
        int valid = (wss >= 0.0f) && (hss >= 0.0f) && (xc < IMGF) && (yc < IMGF);

        float4 bx = make_float4(px1, py1, px2, py2);
        ((float4*)wsBoxes)[n * PRE_N + r] = bx;
        wsScores[n * PRE_N + r] = score;
        wsValid [n * PRE_N + r] = valid;
    }
}

// ---------------------------------------------------------------------------
// Kernel 2: parallel IoU suppression bit-matrix. block = (image, row-tile of 64).
// mask[n][r][w] bit c set iff j = w*64+c > r, j < 2000, iou(r,j) > thresh.
// ---------------------------------------------------------------------------
__global__ __launch_bounds__(256) void nms_mask(
    const float* __restrict__ wsBoxes, uint64_t* __restrict__ mask)
{
    const int blk  = blockIdx.x;
    const int n    = blk >> 5;
    const int i_t  = blk & 31;
    const int tid  = threadIdx.x;
    const int lane = tid & 63;
    const int wv   = tid >> 6;   // 0..3

    __shared__ float cx1[PRE_N], cy1[PRE_N], cx2[PRE_N], cy2[PRE_N], car[PRE_N];
    __shared__ uint64_t tile[64 * 32];   // [row_local][word]

    for (int i = tid; i < PRE_N; i += 256) {
        float4 b = ((const float4*)wsBoxes)[n * PRE_N + i];
        cx1[i] = b.x; cy1[i] = b.y; cx2[i] = b.z; cy2[i] = b.w;
        car[i] = (b.z - b.x + 1.0f) * (b.w - b.y + 1.0f);
    }
    __syncthreads();

    const int r = i_t * 64 + lane;
    const bool rok = (r < PRE_N);
    float x1r = 0.f, y1r = 0.f, x2r = 0.f, y2r = 0.f, ar = 0.f;
    if (rok) { x1r = cx1[r]; y1r = cy1[r]; x2r = cx2[r]; y2r = cy2[r]; ar = car[r]; }

    for (int j_t = wv; j_t < 32; j_t += 4) {
        uint64_t wbits = 0ull;
        if (rok && j_t >= i_t) {
            const int jbase = j_t * 64;
            for (int c = 0; c < 64; ++c) {
                const int j = jbase + c;
                if (j > r && j < PRE_N) {
                    float xx1 = fmaxf(x1r, cx1[j]), yy1 = fmaxf(y1r, cy1[j]);
                    float xx2 = fminf(x2r, cx2[j]), yy2 = fminf(y2r, cy2[j]);
                    float ww = fmaxf(xx2 - xx1 + 1.0f, 0.0f);
                    float hh = fmaxf(yy2 - yy1 + 1.0f, 0.0f);
                    float inter = ww * hh;
                    float iou = inter / (ar + car[j] - inter);
                    if (iou > NMS_TH) wbits |= (1ull << c);
                }
            }
        }
        tile[lane * 32 + j_t] = wbits;
    }
    __syncthreads();

    uint64_t* dst = mask + ((size_t)n * PRE_N + (size_t)i_t * 64) * 32;
    const int lim = (i_t == 31) ? (16 * 32) : (64 * 32);  // rows >= 2000 don't exist
    for (int q = tid; q < lim; q += 256) dst[q] = tile[q];
}

// ---------------------------------------------------------------------------
// Kernel 3: serial greedy scan. INLINE ASM: the compiler provably sinks
// source-level prefetch (R3: scratch ring 152us; R4: named-var ring demand-
// serialized 558us). Here a 20-slot register ring of global_load_dword is
// pinned 20 rows ahead with explicit s_waitcnt vmcnt(19). Lane l owns u32
// word l of the 2048-bit removed vector; decision = v_readlane + scalar test.
// ---------------------------------------------------------------------------
#define NMS_LOAD(n) \
    "global_load_dword %" #n ", %[voff], %[sbase]\n\t" \
    "v_add_u32 %[voff], 0x100, %[voff]\n\t"

#define NMS_STEP(n) \
    "s_waitcnt vmcnt(19)\n\t" \
    "s_lshr_b32 %[sw], %[si], 5\n\t" \
    "v_readlane_b32 %[st], %[rem], %[sw]\n\t" \
    "s_lshr_b32 %[st], %[st], %[si]\n\t" \
    "s_and_b32 %[st], %[st], 1\n\t" \
    "s_cmp_eq_u32 %[st], 0\n\t" \
    "s_cselect_b32 %[sm], -1, 0\n\t" \
    "v_and_b32 %" #n ", %[sm], %" #n "\n\t" \
    "v_or_b32 %[rem], %[rem], %" #n "\n\t" \
    "global_load_dword %" #n ", %[voff], %[sbase]\n\t" \
    "v_add_u32 %[voff], 0x100, %[voff]\n\t" \
    "s_add_u32 %[si], %[si], 1\n\t"

#define NMS_TAIL(n) \
    "s_lshr_b32 %[sw], %[si], 5\n\t" \
    "v_readlane_b32 %[st], %[rem], %[sw]\n\t" \
    "s_lshr_b32 %[st], %[st], %[si]\n\t" \
    "s_and_b32 %[st], %[st], 1\n\t" \
    "s_cmp_eq_u32 %[st], 0\n\t" \
    "s_cselect_b32 %[sm], -1, 0\n\t" \
    "v_and_b32 %" #n ", %[sm], %" #n "\n\t" \
    "v_or_b32 %[rem], %[rem], %" #n "\n\t" \
    "s_add_u32 %[si], %[si], 1\n\t"

__global__ __launch_bounds__(256) void nms_scan_select(
    const float* __restrict__ wsBoxes, const float* __restrict__ wsScores,
    const int* __restrict__ wsValid, const uint64_t* __restrict__ mask,
    float* __restrict__ out)
{
    const int n   = blockIdx.x;
    const int tid = threadIdx.x;

    __shared__ unsigned char invb[256];
    __shared__ unsigned int keepw32[64];
    __shared__ int sscan[256];

    // build "initially removed" (= !valid) bits, 8 boxes per thread
    unsigned int byte = 0u;
    if (tid < PRE_N / 8) {
        for (int q = 0; q < 8; ++q)
            byte |= (wsValid[n * PRE_N + tid * 8 + q] ? 0u : 1u) << q;
    }
    invb[tid] = (unsigned char)byte;
    __syncthreads();

    if (tid < 64) {
        // lane tid owns u32 word tid (bits 32*tid .. 32*tid+31) of removed
        unsigned int rem  = ((const unsigned int*)invb)[tid];
        unsigned long long sbase =
            (unsigned long long)(const void*)(mask + (size_t)n * PRE_N * 32);
        unsigned int voff = (unsigned int)(tid * 4);   // row 0, word tid

        unsigned int r0=0,r1=0,r2=0,r3=0,r4=0,r5=0,r6=0,r7=0,r8=0,r9=0,
                     r10=0,r11=0,r12=0,r13=0,r14=0,r15=0,r16=0,r17=0,r18=0,r19=0;
        int si_, sw_, st_, sm_, scnt_;

        asm volatile(
            "s_waitcnt vmcnt(0) lgkmcnt(0)\n\t"
            NMS_LOAD(0)  NMS_LOAD(1)  NMS_LOAD(2)  NMS_LOAD(3)  NMS_LOAD(4)
            NMS_LOAD(5)  NMS_LOAD(6)  NMS_LOAD(7)  NMS_LOAD(8)  NMS_LOAD(9)
            NMS_LOAD(10) NMS_LOAD(11) NMS_LOAD(12) NMS_LOAD(13) NMS_LOAD(14)
            NMS_LOAD(15) NMS_LOAD(16) NMS_LOAD(17) NMS_LOAD(18) NMS_LOAD(19)
            "s_mov_b32 %[si], 0\n\t"
            "s_mov_b32 %[scnt], 99\n\t"
            "Lnms_%=:\n\t"
            NMS_STEP(0)  NMS_STEP(1)  NMS_STEP(2)  NMS_STEP(3)  NMS_STEP(4)
            NMS_STEP(5)  NMS_STEP(6)  NMS_STEP(7)  NMS_STEP(8)  NMS_STEP(9)
            NMS_STEP(10) NMS_STEP(11) NMS_STEP(12) NMS_STEP(13) NMS_STEP(14)
            NMS_STEP(15) NMS_STEP(16) NMS_STEP(17) NMS_STEP(18) NMS_STEP(19)
            "s_sub_u32 %[scnt], %[scnt], 1\n\t"
            "s_cmp_lg_u32 %[scnt], 0\n\t"
            "s_cbranch_scc1 Lnms_%=\n\t"
            "s_waitcnt vmcnt(0)\n\t"
            NMS_TAIL(0)  NMS_TAIL(1)  NMS_TAIL(2)  NMS_TAIL(3)  NMS_TAIL(4)
            NMS_TAIL(5)  NMS_TAIL(6)  NMS_TAIL(7)  NMS_TAIL(8)  NMS_TAIL(9)
            NMS_TAIL(10) NMS_TAIL(11) NMS_TAIL(12) NMS_TAIL(13) NMS_TAIL(14)
            NMS_TAIL(15) NMS_TAIL(16) NMS_TAIL(17) NMS_TAIL(18) NMS_TAIL(19)
            : "+v"(r0),  "+v"(r1),  "+v"(r2),  "+v"(r3),  "+v"(r4),
              "+v"(r5),  "+v"(r6),  "+v"(r7),  "+v"(r8),  "+v"(r9),
              "+v"(r10), "+v"(r11), "+v"(r12), "+v"(r13), "+v"(r14),
              "+v"(r15), "+v"(r16), "+v"(r17), "+v"(r18), "+v"(r19),
              [rem]"+v"(rem), [voff]"+v"(voff),
              [si]"=&s"(si_), [sw]"=&s"(sw_), [st]"=&s"(st_),
              [sm]"=&s"(sm_), [scnt]"=&s"(scnt_)
            : [sbase]"s"(sbase)
            : "vcc", "memory");

        unsigned int kw = ~rem;
        if (tid == 62) kw &= 0xFFFFu;   // rows 1984..1999 only
        if (tid == 63) kw = 0u;         // rows 2016+ don't exist
        keepw32[tid] = kw;
    }
    __syncthreads();

    // prefix scan of keep flags, 8 per thread
    int c[8]; const int base8 = tid * 8;
    int lsum = 0;
    for (int q = 0; q < 8; ++q) {
        const int i = base8 + q;
        c[q] = (i < PRE_N) ? (int)((keepw32[i >> 5] >> (i & 31)) & 1u) : 0;
        lsum += c[q];
    }
    sscan[tid] = lsum;
    __syncthreads();
    for (int off = 1; off < 256; off <<= 1) {
        int v = (tid >= off) ? sscan[tid - off] : 0;
        __syncthreads();
        sscan[tid] += v;
        __syncthreads();
    }
    const int excl  = sscan[tid] - lsum;
    const int total = sscan[255];

    float* ob  = out + n * POST_N * 4;
    float* osc = out + NIMG * POST_N * 4 + n * POST_N;
    float* ovd = out + NIMG * POST_N * 5 + n * POST_N;

    for (int i = tid; i < POST_N * 4; i += 256) ob[i] = 0.0f;
    for (int i = tid; i < POST_N; i += 256) osc[i] = 0.0f;
    const int lim = min(total, POST_N);
    for (int i = tid; i < POST_N; i += 256) ovd[i] = (i < lim) ? 1.0f : 0.0f;
    __syncthreads();

    int run = excl;
    for (int q = 0; q < 8; ++q) {
        const int i = base8 + q;
        if (i < PRE_N && c[q]) {
            if (run < POST_N) {
                float4 b = ((const float4*)wsBoxes)[n * PRE_N + i];
                ob[run * 4 + 0] = b.x;
                ob[run * 4 + 1] = b.y;
                ob[run * 4 + 2] = b.z;
                ob[run * 4 + 3] = b.w;
                osc[run] = wsScores[n * PRE_N + i];
            }
            run++;
        }
    }
}

extern "C" void kernel_launch(void* const* d_in, const int* in_sizes, int n_in,
                              void* d_out, int out_size, void* d_ws, size_t ws_size,
                              hipStream_t stream) {
    const float* obj  = (const float*)d_in[0];
    const float* breg = (const float*)d_in[1];
    // d_in[2] anchors unused (computed inline, exact in f32)
    float* ws        = (float*)d_ws;
    float* wsBoxes   = ws;                      // 64000 floats
    float* wsScores  = ws + 64000;              // 16000 floats
    int*   wsValid   = (int*)(ws + 80000);      // 16000 ints
    uint64_t* wsMask = (uint64_t*)(ws + 96000); // 8*2000*32 u64 = 4 MB

    topk_decode<<<NIMG, 1024, 0, stream>>>(obj, breg, wsBoxes, wsScores, wsValid);
    nms_mask<<<NIMG * 32, 256, 0, stream>>>(wsBoxes, wsMask);
    nms_scan_select<<<NIMG, 256, 0, stream>>>(wsBoxes, wsScores, wsValid, wsMask,
                                              (float*)d_out);
}